// Round 1
// baseline (53.919 us; speedup 1.0000x reference)
//
#include <hip/hip_runtime.h>

// WaveletMask: y = HaarInv( HaarFwd(x) .* weight-mosaic )
// x, weight: (1,1,128,128) fp32; y: (1,1,128,128) fp32.
//
// Per 2x2 block (i,j), i,j in [0,64):
//   a=x[2i,2j] b=x[2i,2j+1] c=x[2i+1,2j] d=x[2i+1,2j+1]
//   ll=(a+b+c+d)/2  lh=(a+b-c-d)/2  hl=(a-b+c-d)/2  hh=(a-b-c+d)/2
//   ll*=W[i,j]; lh*=W[i,j+64]; hl*=W[i+64,j]; hh*=W[i+64,j+64]
//   y[2i,2j]  =(ll+lh+hl+hh)/2   y[2i,2j+1]=(ll+lh-hl-hh)/2
//   y[2i+1,2j]=(ll-lh+hl-hh)/2   y[2i+1,2j+1]=(ll-lh-hl+hh)/2

#define H 128
#define HB 64

__global__ __launch_bounds__(256) void wavelet_mask_kernel(
    const float* __restrict__ x, const float* __restrict__ w,
    float* __restrict__ y) {
    int t = blockIdx.x * blockDim.x + threadIdx.x;  // 0..4095
    int i = t >> 6;        // block row, 0..63
    int j = t & 63;        // block col, 0..63

    // x rows 2i and 2i+1, columns 2j..2j+1 -> float2 loads
    const float2* xr0 = reinterpret_cast<const float2*>(x + (2 * i) * H);
    const float2* xr1 = reinterpret_cast<const float2*>(x + (2 * i + 1) * H);
    float2 top = xr0[j];   // a, b
    float2 bot = xr1[j];   // c, d
    float a = top.x, b = top.y, c = bot.x, d = bot.y;

    float ll = (a + b + c + d) * 0.5f;
    float lh = (a + b - c - d) * 0.5f;
    float hl = (a - b + c - d) * 0.5f;
    float hh = (a - b - c + d) * 0.5f;

    // weight mosaic
    ll *= w[i * H + j];
    lh *= w[i * H + j + HB];
    hl *= w[(i + HB) * H + j];
    hh *= w[(i + HB) * H + j + HB];

    float oa = (ll + lh + hl + hh) * 0.5f;
    float ob = (ll + lh - hl - hh) * 0.5f;
    float oc = (ll - lh + hl - hh) * 0.5f;
    float od = (ll - lh - hl + hh) * 0.5f;

    float2* yr0 = reinterpret_cast<float2*>(y + (2 * i) * H);
    float2* yr1 = reinterpret_cast<float2*>(y + (2 * i + 1) * H);
    yr0[j] = make_float2(oa, ob);
    yr1[j] = make_float2(oc, od);
}

extern "C" void kernel_launch(void* const* d_in, const int* in_sizes, int n_in,
                              void* d_out, int out_size, void* d_ws, size_t ws_size,
                              hipStream_t stream) {
    const float* x = (const float*)d_in[0];
    const float* w = (const float*)d_in[1];
    float* y = (float*)d_out;
    // 64*64 = 4096 blocks-of-2x2, one thread each
    wavelet_mask_kernel<<<16, 256, 0, stream>>>(x, w, y);
}